// Round 10
// baseline (516.142 us; speedup 1.0000x reference)
//
#include <hip/hip_runtime.h>
#include <hip/hip_cooperative_groups.h>
#include <stdint.h>

#define NR 8192
#define FD 256
#define NCH 1024   // 8-row chunks

typedef __attribute__((ext_vector_type(8))) short bf16x8;
typedef __attribute__((ext_vector_type(4))) float f32x4;

namespace cg = cooperative_groups;

__device__ __forceinline__ float leaky_f(float z){ return z >= 0.0f ? z : 0.1f * z; }

__device__ __forceinline__ unsigned short f2bf(float f){
    union { float f; uint32_t u; } v; v.f = f;
    uint32_t r = v.u + 0x7fffu + ((v.u >> 16) & 1u);
    return (unsigned short)(r >> 16);
}
__device__ __forceinline__ float bf2f(unsigned short h){
    union { uint32_t u; float f; } v; v.u = ((uint32_t)h) << 16;
    return v.f;
}

// ===========================================================================
// All phases are __device__ functions of (b in [0,512), tid in [0,256)).
// mega calls them with grid.sync() between; fallback wrappers launch each.
// ===========================================================================

// ---- Phase A: weight hi/lo planes, s,t, x hi/lo planes, zero rank/pos -----
__device__ __forceinline__ void phaseA(int b, int tid,
    const float* __restrict__ x,  const float* __restrict__ W3,
    const float* __restrict__ W6, const float* __restrict__ W5,
    float* __restrict__ s, float* __restrict__ t,
    int* __restrict__ rank, int* __restrict__ pos,
    short* __restrict__ xhi, short* __restrict__ xlo,
    short* __restrict__ W6hi, short* __restrict__ W6lo,
    short* __restrict__ W5hi, short* __restrict__ W5lo)
{
    int gt = b * 256 + tid;                    // 512*256 == 2*FD*FD exactly
    {
        bool six = gt < FD * FD;
        const float* W = six ? W6 : W5;
        short* hi = six ? W6hi : W5hi;
        short* lo = six ? W6lo : W5lo;
        int k = six ? gt : gt - FD * FD;
        float v = W[k];
        unsigned short h = f2bf(v);
        hi[k] = (short)h;
        lo[k] = (short)f2bf(v - bf2f(h));
    }
    if (gt < NR){ rank[gt] = 0; pos[gt] = 0; }
    int wave = tid >> 6, lane = tid & 63;
    int w = b * 4 + wave;                      // 2048 waves x 4 rows
    const float4* wa = (const float4*)W3;
    const float4* wb = (const float4*)(W3 + FD);
    float4 av = wa[lane], bv = wb[lane];
    #pragma unroll
    for (int rr = 0; rr < 4; ++rr){
        int row = w * 4 + rr;
        float4 xv = ((const float4*)(x + (size_t)row * FD))[lane];
        float xe[4] = {xv.x, xv.y, xv.z, xv.w};
        short4 h4, l4;
        short* hp = &h4.x; short* lp = &l4.x;
        #pragma unroll
        for (int e = 0; e < 4; ++e){
            unsigned short h = f2bf(xe[e]);
            hp[e] = (short)h;
            lp[e] = (short)f2bf(xe[e] - bf2f(h));
        }
        *reinterpret_cast<short4*>(xhi + (size_t)row * FD + lane * 4) = h4;
        *reinterpret_cast<short4*>(xlo + (size_t)row * FD + lane * 4) = l4;
        float as = xv.x*av.x + xv.y*av.y + xv.z*av.z + xv.w*av.w;
        float at = xv.x*bv.x + xv.y*bv.y + xv.z*bv.z + xv.w*bv.w;
        #pragma unroll
        for (int off = 32; off > 0; off >>= 1){
            as += __shfl_xor(as, off, 64);
            at += __shfl_xor(at, off, 64);
        }
        if (lane == 0){ s[row] = as; t[row] = at; }
    }
}

// ---- Phase B: rank/pos counting (one 512-value span per block, exact) -----
__device__ __forceinline__ void phaseB(int b, int tid,
    const float* __restrict__ t, const float* __restrict__ s,
    const float* __restrict__ b3,
    int* __restrict__ rank, int* __restrict__ pos)
{
    __shared__ __align__(16) float seg[512];
    int j = (b >> 4) * 256 + tid;              // 32 j-groups
    int segBase = (b & 15) * 512;              // 16 x 512-value spans
    seg[tid]       = t[segBase + tid];
    seg[tid + 256] = t[segBase + tid + 256];
    __syncthreads();
    float tj = t[j];
    float theta = -(s[j] + b3[0]);
    int cr = 0, cp = 0;
    #pragma unroll 8
    for (int r = 0; r < 512; r += 4){
        float4 v = *reinterpret_cast<const float4*>(&seg[r]);
        int jp = segBase + r;
        cr += (v.x < tj) || (v.x == tj && (jp + 0) < j);
        cr += (v.y < tj) || (v.y == tj && (jp + 1) < j);
        cr += (v.z < tj) || (v.z == tj && (jp + 2) < j);
        cr += (v.w < tj) || (v.w == tj && (jp + 3) < j);
        cp += (v.x < theta);
        cp += (v.y < theta);
        cp += (v.z < theta);
        cp += (v.w < theta);
    }
    atomicAdd(&rank[j], cr);
    atomicAdd(&pos[j], cp);
}

// ---- GEMM phase (R3-proven geometry): 64x64 tile, 4 waves, full K ---------
template<bool SCATTER, bool ADD>
__device__ __forceinline__ void gemm_phase(int b, int tid,
    const short* __restrict__ Ahi, const short* __restrict__ Alo,
    const short* __restrict__ Whi, const short* __restrict__ Wlo,
    const float* __restrict__ bias, const float* __restrict__ addend,
    const int* __restrict__ perm, const float* __restrict__ tvals,
    float* __restrict__ tsorted, float* __restrict__ out)
{
    int wave = tid >> 6, lane = tid & 63;
    int tileRow = b >> 2;                      // 128 rowtiles x 4 coltiles
    int rowBase = tileRow * 64 + wave * 16;
    int colBase = (b & 3) * 64;

    if (SCATTER && (b & 3) == 0 && tid < 64){  // fused ts[rank[i]] = t[i]
        int row = tileRow * 64 + tid;
        tsorted[perm[row]] = tvals[row];
    }

    int m16 = lane & 15, k8 = (lane >> 4) * 8;
    f32x4 acc[4];
    #pragma unroll
    for (int c = 0; c < 4; ++c) acc[c] = (f32x4){0.f, 0.f, 0.f, 0.f};

    const short* arh = Ahi + (size_t)(rowBase + m16) * FD + k8;
    const short* arl = Alo + (size_t)(rowBase + m16) * FD + k8;

    #pragma unroll
    for (int ks = 0; ks < 8; ++ks){
        int kb = ks * 32;
        bf16x8 ahi = *reinterpret_cast<const bf16x8*>(arh + kb);
        bf16x8 alo = *reinterpret_cast<const bf16x8*>(arl + kb);
        #pragma unroll
        for (int c = 0; c < 4; ++c){
            size_t boff = (size_t)(colBase + c * 16 + m16) * FD + k8 + kb;
            bf16x8 bhi = *reinterpret_cast<const bf16x8*>(Whi + boff);
            bf16x8 blo = *reinterpret_cast<const bf16x8*>(Wlo + boff);
            acc[c] = __builtin_amdgcn_mfma_f32_16x16x32_bf16(ahi, bhi, acc[c], 0, 0, 0);
            acc[c] = __builtin_amdgcn_mfma_f32_16x16x32_bf16(alo, bhi, acc[c], 0, 0, 0);
            acc[c] = __builtin_amdgcn_mfma_f32_16x16x32_bf16(ahi, blo, acc[c], 0, 0, 0);
        }
    }

    int rq = (lane >> 4) * 4;
    #pragma unroll
    for (int c = 0; c < 4; ++c){
        int gcol = colBase + c * 16 + m16;
        float bs = bias[gcol];
        #pragma unroll
        for (int j = 0; j < 4; ++j){
            int grow = rowBase + rq + j;
            float v = leaky_f(acc[c][j] + bs);
            if (ADD) v += addend[(size_t)grow * FD + gcol];
            int orow = SCATTER ? perm[grow] : grow;
            out[(size_t)orow * FD + gcol] = v;
        }
    }
}

// ---- Phase D: per-chunk (8-row) column sums, 2 chunks/block ---------------
__device__ __forceinline__ void phaseD(int b, int tid,
    const float* __restrict__ Gs, const float* __restrict__ ts,
    float* __restrict__ p0, float* __restrict__ p1)
{
    int col = tid;
    #pragma unroll
    for (int c2 = 0; c2 < 2; ++c2){
        int chunk = b * 2 + c2;
        int base = chunk * 8;
        float s0 = 0.f, s1 = 0.f;
        #pragma unroll
        for (int r = 0; r < 8; ++r){
            float g = Gs[(size_t)(base + r) * FD + col];
            s0 += g;
            s1 += ts[base + r] * g;
        }
        p0[(size_t)chunk * FD + col] = s0;
        p1[(size_t)chunk * FD + col] = s1;
    }
}

// ---- Phase E: exclusive column scan of 1024 chunk partials (b<128) --------
__device__ __forceinline__ void phaseE(int b, int tid,
    float* __restrict__ p0, float* __restrict__ p1)
{
    int wave = tid >> 6, lane = tid & 63;
    int w = b * 4 + wave;                      // [0,512)
    float* p = (w < 256) ? p0 : p1;
    int col = w & 255;
    int c0 = lane * 16;
    float v[16];
    #pragma unroll
    for (int k = 0; k < 16; ++k) v[k] = p[(size_t)(c0 + k) * FD + col];
    float run = 0.f;
    #pragma unroll
    for (int k = 0; k < 16; ++k) run += v[k];
    float xx = run;
    #pragma unroll
    for (int off = 1; off < 64; off <<= 1){
        float n = __shfl_up(xx, off, 64);
        if (lane >= off) xx += n;
    }
    float e = xx - run;
    #pragma unroll
    for (int k = 0; k < 16; ++k){
        p[(size_t)(c0 + k) * FD + col] = e;
        e += v[k];
    }
    if (lane == 63) p[(size_t)NCH * FD + col] = xx;
}

// ---- Phase F: M -> bf16 hi/lo planes, 16 rows/block -----------------------
__device__ __forceinline__ void phaseF(int b, int tid,
    const float* __restrict__ s, const float* __restrict__ t,
    const float* __restrict__ b3,
    const int* __restrict__ rank, const int* __restrict__ pos,
    const float* __restrict__ ts, const float* __restrict__ Gs,
    const float* __restrict__ p0, const float* __restrict__ p1,
    short* __restrict__ Mhi, short* __restrict__ Mlo)
{
    int col = tid;
    int i0 = b * 16;
    float T0 = p0[(size_t)NCH * FD + col];
    float T1 = p1[(size_t)NCH * FD + col];
    float c = b3[0];
    const float inv = 1.0f / (float)(NR - 1);
    for (int r = 0; r < 16; ++r){
        int i = i0 + r;
        float sic = s[i] + c;
        float diag = leaky_f(sic + t[i]);
        int ps = pos[i];
        int rk = rank[i];
        int ch = ps >> 3;
        float P0 = p0[(size_t)ch * FD + col];
        float P1 = p1[(size_t)ch * FD + col];
        for (int r2 = ch * 8; r2 < ps; ++r2){   // <=7 iters, uniform
            float g2 = Gs[(size_t)r2 * FD + col];
            P0 += g2;
            P1 += ts[r2] * g2;
        }
        float g = Gs[(size_t)rk * FD + col];
        float full = sic * T0 + T1;
        float act  = sic * (T0 - P0) + (T1 - P1);
        float m = (0.1f * full + 0.9f * act - diag * g) * inv;
        unsigned short h = f2bf(m);
        Mhi[(size_t)i * FD + col] = (short)h;
        Mlo[(size_t)i * FD + col] = (short)f2bf(m - bf2f(h));
    }
}

// ===========================================================================
// mega: all 7 phases, 6 grid syncs. 512 blocks x 256 threads = 2 blocks/CU
// needed for co-residency (large margin; launch_bounds caps at 256 VGPR).
// ===========================================================================
__global__ __launch_bounds__(256, 2) void mega(
    const float* __restrict__ x,  const float* __restrict__ W3,
    const float* __restrict__ b3, const float* __restrict__ W6,
    const float* __restrict__ b6, const float* __restrict__ W5,
    const float* __restrict__ b5, float* __restrict__ out,
    float* __restrict__ s, float* __restrict__ t, float* __restrict__ ts,
    int* __restrict__ rank, int* __restrict__ pos,
    float* __restrict__ p0, float* __restrict__ p1,
    short* __restrict__ W6hi, short* __restrict__ W6lo,
    short* __restrict__ W5hi, short* __restrict__ W5lo,
    short* __restrict__ xhi, short* __restrict__ xlo,
    short* __restrict__ Mhi, short* __restrict__ Mlo,
    float* __restrict__ Gs)
{
    cg::grid_group grid = cg::this_grid();
    int b = blockIdx.x, tid = threadIdx.x;

    phaseA(b, tid, x, W3, W6, W5, s, t, rank, pos, xhi, xlo,
           W6hi, W6lo, W5hi, W5lo);
    grid.sync();
    phaseB(b, tid, t, s, b3, rank, pos);
    grid.sync();
    gemm_phase<true, false>(b, tid, xhi, xlo, W6hi, W6lo, b6, nullptr,
                            rank, t, ts, Gs);
    grid.sync();
    phaseD(b, tid, Gs, ts, p0, p1);
    grid.sync();
    if (b < 128) phaseE(b, tid, p0, p1);
    grid.sync();
    phaseF(b, tid, s, t, b3, rank, pos, ts, Gs, p0, p1, Mhi, Mlo);
    grid.sync();
    gemm_phase<false, true>(b, tid, Mhi, Mlo, W5hi, W5lo, b5, x,
                            nullptr, nullptr, nullptr, out);
}

// ---- fallback wrappers (identical phases as separate dispatches) ----------
__global__ __launch_bounds__(256) void kA(
    const float* x, const float* W3, const float* W6, const float* W5,
    float* s, float* t, int* rank, int* pos, short* xhi, short* xlo,
    short* W6hi, short* W6lo, short* W5hi, short* W5lo){
    phaseA(blockIdx.x, threadIdx.x, x, W3, W6, W5, s, t, rank, pos,
           xhi, xlo, W6hi, W6lo, W5hi, W5lo);
}
__global__ __launch_bounds__(256) void kB(
    const float* t, const float* s, const float* b3, int* rank, int* pos){
    phaseB(blockIdx.x, threadIdx.x, t, s, b3, rank, pos);
}
template<bool SCATTER, bool ADD>
__global__ __launch_bounds__(256) void kGemm(
    const short* Ahi, const short* Alo, const short* Whi, const short* Wlo,
    const float* bias, const float* addend, const int* perm,
    const float* tvals, float* tsorted, float* out){
    gemm_phase<SCATTER, ADD>(blockIdx.x, threadIdx.x, Ahi, Alo, Whi, Wlo,
                             bias, addend, perm, tvals, tsorted, out);
}
__global__ __launch_bounds__(256) void kD(
    const float* Gs, const float* ts, float* p0, float* p1){
    phaseD(blockIdx.x, threadIdx.x, Gs, ts, p0, p1);
}
__global__ __launch_bounds__(256) void kE(float* p0, float* p1){
    phaseE(blockIdx.x, threadIdx.x, p0, p1);
}
__global__ __launch_bounds__(256) void kF(
    const float* s, const float* t, const float* b3, const int* rank,
    const int* pos, const float* ts, const float* Gs,
    const float* p0, const float* p1, short* Mhi, short* Mlo){
    phaseF(blockIdx.x, threadIdx.x, s, t, b3, rank, pos, ts, Gs, p0, p1,
           Mhi, Mlo);
}

// ---------------------------------------------------------------------------
extern "C" void kernel_launch(void* const* d_in, const int* in_sizes, int n_in,
                              void* d_out, int out_size, void* d_ws, size_t ws_size,
                              hipStream_t stream)
{
    const float* x  = (const float*)d_in[0];
    const float* W3 = (const float*)d_in[1];
    const float* b3 = (const float*)d_in[2];
    const float* W6 = (const float*)d_in[3];
    const float* b6 = (const float*)d_in[4];
    const float* W5 = (const float*)d_in[5];
    const float* b5 = (const float*)d_in[6];
    float* out = (float*)d_out;

    char* ws = (char*)d_ws;
    size_t off = 0;
    auto alloc = [&](size_t bytes) -> void* {
        void* p = ws + off;
        off += (bytes + 255) & ~(size_t)255;
        return p;
    };
    float*  s    = (float*)alloc(NR * 4);
    float*  t    = (float*)alloc(NR * 4);
    float*  ts   = (float*)alloc(NR * 4);
    int*    rank = (int*)  alloc(NR * 4);
    int*    pos  = (int*)  alloc(NR * 4);
    float*  p0   = (float*)alloc((size_t)(NCH + 1) * FD * 4);
    float*  p1   = (float*)alloc((size_t)(NCH + 1) * FD * 4);
    short*  W6hi = (short*)alloc(FD * FD * 2);
    short*  W6lo = (short*)alloc(FD * FD * 2);
    short*  W5hi = (short*)alloc(FD * FD * 2);
    short*  W5lo = (short*)alloc(FD * FD * 2);
    short*  xhi  = (short*)alloc((size_t)NR * FD * 2);
    short*  xlo  = (short*)alloc((size_t)NR * FD * 2);
    short*  Mhi  = (short*)alloc((size_t)NR * FD * 2);
    short*  Mlo  = (short*)alloc((size_t)NR * FD * 2);
    float*  Gs   = (float*)alloc((size_t)NR * FD * 4);
    (void)ws_size; (void)in_sizes; (void)n_in; (void)out_size;

    void* args[] = {
        (void*)&x, (void*)&W3, (void*)&b3, (void*)&W6, (void*)&b6,
        (void*)&W5, (void*)&b5, (void*)&out,
        (void*)&s, (void*)&t, (void*)&ts, (void*)&rank, (void*)&pos,
        (void*)&p0, (void*)&p1,
        (void*)&W6hi, (void*)&W6lo, (void*)&W5hi, (void*)&W5lo,
        (void*)&xhi, (void*)&xlo, (void*)&Mhi, (void*)&Mlo, (void*)&Gs
    };
    hipError_t e = hipLaunchCooperativeKernel((const void*)mega, dim3(512),
                                              dim3(256), args, 0, stream);
    if (e != hipSuccess){
        (void)hipGetLastError();   // clear, then run identical phases split
        kA<<<dim3(512), dim3(256), 0, stream>>>(
            x, W3, W6, W5, s, t, rank, pos, xhi, xlo, W6hi, W6lo, W5hi, W5lo);
        kB<<<dim3(512), dim3(256), 0, stream>>>(t, s, b3, rank, pos);
        kGemm<true, false><<<dim3(512), dim3(256), 0, stream>>>(
            xhi, xlo, W6hi, W6lo, b6, nullptr, rank, t, ts, Gs);
        kD<<<dim3(512), dim3(256), 0, stream>>>(Gs, ts, p0, p1);
        kE<<<dim3(128), dim3(256), 0, stream>>>(p0, p1);
        kF<<<dim3(512), dim3(256), 0, stream>>>(
            s, t, b3, rank, pos, ts, Gs, p0, p1, Mhi, Mlo);
        kGemm<false, true><<<dim3(512), dim3(256), 0, stream>>>(
            Mhi, Mlo, W5hi, W5lo, b5, x, nullptr, nullptr, nullptr, out);
    }
}

// Round 16
// 162.599 us; speedup vs baseline: 3.1743x; 3.1743x over previous
//
#include <hip/hip_runtime.h>
#include <stdint.h>

#define NR 8192
#define FD 256
#define NCH 1024   // 8-row chunks

typedef __attribute__((ext_vector_type(8))) short bf16x8;
typedef __attribute__((ext_vector_type(4))) float f32x4;

__device__ __forceinline__ float leaky_f(float z){ return z >= 0.0f ? z : 0.1f * z; }

__device__ __forceinline__ unsigned short f2bf(float f){
    union { float f; uint32_t u; } v; v.f = f;
    uint32_t r = v.u + 0x7fffu + ((v.u >> 16) & 1u);
    return (unsigned short)(r >> 16);
}
__device__ __forceinline__ float bf2f(unsigned short h){
    union { uint32_t u; float f; } v; v.u = ((uint32_t)h) << 16;
    return v.f;
}

// ---------------------------------------------------------------------------
// kA: blocks [0,512): weight bf16 hi/lo planes; [512,2560): s,t + x planes
// + zero rank/pos. 2560 blocks for TLP.
__global__ __launch_bounds__(256) void kA(
    const float* __restrict__ x,  const float* __restrict__ W3,
    const float* __restrict__ W6, const float* __restrict__ W5,
    float* __restrict__ s, float* __restrict__ t,
    int* __restrict__ rank, int* __restrict__ pos,
    short* __restrict__ xhi, short* __restrict__ xlo,
    short* __restrict__ W6hi, short* __restrict__ W6lo,
    short* __restrict__ W5hi, short* __restrict__ W5lo)
{
    int b = blockIdx.x, tid = threadIdx.x;
    if (b < 512){
        int i = b * 256 + tid;                 // [0, 131072)
        bool six = i < FD * FD;
        const float* W = six ? W6 : W5;
        short* hi = six ? W6hi : W5hi;
        short* lo = six ? W6lo : W5lo;
        int k = six ? i : i - FD * FD;
        float v = W[k];
        unsigned short h = f2bf(v);
        hi[k] = (short)h;
        lo[k] = (short)f2bf(v - bf2f(h));
        return;
    }
    int wave = tid >> 6, lane = tid & 63;
    int row = (b - 512) * 4 + wave;
    const float4* wa = (const float4*)W3;
    const float4* wb = (const float4*)(W3 + FD);
    float4 av = wa[lane], bv = wb[lane];
    float4 xv = ((const float4*)(x + (size_t)row * FD))[lane];
    float xe[4] = {xv.x, xv.y, xv.z, xv.w};
    short4 h4, l4;
    short* hp = &h4.x; short* lp = &l4.x;
    #pragma unroll
    for (int e = 0; e < 4; ++e){
        unsigned short h = f2bf(xe[e]);
        hp[e] = (short)h;
        lp[e] = (short)f2bf(xe[e] - bf2f(h));
    }
    *reinterpret_cast<short4*>(xhi + (size_t)row * FD + lane * 4) = h4;
    *reinterpret_cast<short4*>(xlo + (size_t)row * FD + lane * 4) = l4;
    float as = xv.x*av.x + xv.y*av.y + xv.z*av.z + xv.w*av.w;
    float at = xv.x*bv.x + xv.y*bv.y + xv.z*bv.z + xv.w*bv.w;
    #pragma unroll
    for (int off = 32; off > 0; off >>= 1){
        as += __shfl_xor(as, off, 64);
        at += __shfl_xor(at, off, 64);
    }
    if (lane == 0){ s[row] = as; t[row] = at; rank[row] = 0; pos[row] = 0; }
}

// ---------------------------------------------------------------------------
// kB: rank/pos counting, grid (32,32): j-group x 256-value segment; exact
// int atomics. pos[j] = #{t_r < -(s_j+b3)} == lower_bound(ts, theta_j).
__global__ __launch_bounds__(256) void kB(
    const float* __restrict__ t, const float* __restrict__ s,
    const float* __restrict__ b3,
    int* __restrict__ rank, int* __restrict__ pos)
{
    __shared__ __align__(16) float seg[256];
    int tid = threadIdx.x;
    int j = blockIdx.x * 256 + tid;
    int segBase = blockIdx.y * 256;
    seg[tid] = t[segBase + tid];
    __syncthreads();
    float tj = t[j];
    float theta = -(s[j] + b3[0]);
    int cr = 0, cp = 0;
    #pragma unroll 8
    for (int r = 0; r < 256; r += 4){
        float4 v = *reinterpret_cast<const float4*>(&seg[r]);
        int jp = segBase + r;
        cr += (v.x < tj) || (v.x == tj && (jp + 0) < j);
        cr += (v.y < tj) || (v.y == tj && (jp + 1) < j);
        cr += (v.z < tj) || (v.z == tj && (jp + 2) < j);
        cr += (v.w < tj) || (v.w == tj && (jp + 3) < j);
        cp += (v.x < theta);
        cp += (v.y < theta);
        cp += (v.z < theta);
        cp += (v.w < theta);
    }
    atomicAdd(&rank[j], cr);
    atomicAdd(&pos[j], cp);
}

// ---------------------------------------------------------------------------
// kGemm: out[i][n] = leaky(sum_k A[i][k]*Wt[n][k] + bias[n]) (+ addend)
// 32x64 tile, 4 waves (2 row-halves x 2 col-halves), grid 1024 =
// 4 blocks/CU -> 4 waves/SIMD (2x the latency hiding of the 64x64 version).
// Split-bf16 MFMA (hh+lh+hl), pre-split planes. SCATTER fuses ts scatter.
template<bool SCATTER, bool ADD>
__global__ __launch_bounds__(256) void kGemm(
    const short* __restrict__ Ahi, const short* __restrict__ Alo,
    const short* __restrict__ Whi, const short* __restrict__ Wlo,
    const float* __restrict__ bias, const float* __restrict__ addend,
    const int* __restrict__ perm, const float* __restrict__ tvals,
    float* __restrict__ tsorted, float* __restrict__ out)
{
    int b = blockIdx.x, tid = threadIdx.x;
    int wave = tid >> 6, lane = tid & 63;
    int tileRow = b >> 2;                      // 256 rowtiles x 4 coltiles
    int rowBase = tileRow * 32 + (wave & 1) * 16;
    int colBase = (b & 3) * 64 + (wave >> 1) * 32;

    if (SCATTER && (b & 3) == 0 && tid < 32){  // fused ts[rank[i]] = t[i]
        int row = tileRow * 32 + tid;
        tsorted[perm[row]] = tvals[row];
    }

    int m16 = lane & 15, k8 = (lane >> 4) * 8;
    f32x4 acc[2];
    acc[0] = (f32x4){0.f, 0.f, 0.f, 0.f};
    acc[1] = (f32x4){0.f, 0.f, 0.f, 0.f};

    const short* arh = Ahi + (size_t)(rowBase + m16) * FD + k8;
    const short* arl = Alo + (size_t)(rowBase + m16) * FD + k8;

    #pragma unroll
    for (int ks = 0; ks < 8; ++ks){
        int kb = ks * 32;
        bf16x8 ahi = *reinterpret_cast<const bf16x8*>(arh + kb);
        bf16x8 alo = *reinterpret_cast<const bf16x8*>(arl + kb);
        #pragma unroll
        for (int c = 0; c < 2; ++c){
            size_t boff = (size_t)(colBase + c * 16 + m16) * FD + k8 + kb;
            bf16x8 bhi = *reinterpret_cast<const bf16x8*>(Whi + boff);
            bf16x8 blo = *reinterpret_cast<const bf16x8*>(Wlo + boff);
            acc[c] = __builtin_amdgcn_mfma_f32_16x16x32_bf16(ahi, bhi, acc[c], 0, 0, 0);
            acc[c] = __builtin_amdgcn_mfma_f32_16x16x32_bf16(alo, bhi, acc[c], 0, 0, 0);
            acc[c] = __builtin_amdgcn_mfma_f32_16x16x32_bf16(ahi, blo, acc[c], 0, 0, 0);
        }
    }

    int rq = (lane >> 4) * 4;
    #pragma unroll
    for (int c = 0; c < 2; ++c){
        int gcol = colBase + c * 16 + m16;
        float bs = bias[gcol];
        #pragma unroll
        for (int j = 0; j < 4; ++j){
            int grow = rowBase + rq + j;
            float v = leaky_f(acc[c][j] + bs);
            if (ADD) v += addend[(size_t)grow * FD + gcol];
            int orow = SCATTER ? perm[grow] : grow;
            out[(size_t)orow * FD + gcol] = v;
        }
    }
}

// ---------------------------------------------------------------------------
// kD: per-chunk (8 rows) column sums of Gs and ts*Gs. Grid 1024.
__global__ __launch_bounds__(256) void kD(
    const float* __restrict__ Gs, const float* __restrict__ ts,
    float* __restrict__ p0, float* __restrict__ p1)
{
    int col = threadIdx.x;
    int chunk = blockIdx.x;
    int base = chunk * 8;
    float s0 = 0.f, s1 = 0.f;
    #pragma unroll
    for (int r = 0; r < 8; ++r){
        float g = Gs[(size_t)(base + r) * FD + col];
        s0 += g;
        s1 += ts[base + r] * g;
    }
    p0[(size_t)chunk * FD + col] = s0;
    p1[(size_t)chunk * FD + col] = s1;
}

// ---------------------------------------------------------------------------
// kE: exclusive scan of 1024 chunk partials per column, in place; grand
// total -> row 1024. Grid 512 single-wave blocks (bid<256 -> p0, else p1).
__global__ __launch_bounds__(64) void kE(float* __restrict__ p0,
                                         float* __restrict__ p1)
{
    int bid = blockIdx.x;
    int lane = threadIdx.x;
    float* p = (bid < 256) ? p0 : p1;
    int col = bid & 255;
    int c0 = lane * 16;
    float v[16];
    #pragma unroll
    for (int k = 0; k < 16; ++k) v[k] = p[(size_t)(c0 + k) * FD + col];
    float run = 0.f;
    #pragma unroll
    for (int k = 0; k < 16; ++k) run += v[k];
    float xx = run;
    #pragma unroll
    for (int off = 1; off < 64; off <<= 1){
        float n = __shfl_up(xx, off, 64);
        if (lane >= off) xx += n;
    }
    float e = xx - run;
    #pragma unroll
    for (int k = 0; k < 16; ++k){
        p[(size_t)(c0 + k) * FD + col] = e;
        e += v[k];
    }
    if (lane == 63) p[(size_t)NCH * FD + col] = xx;
}

// ---------------------------------------------------------------------------
// kF: M[i][k] = (0.1*full + 0.9*active - diag_i*G[i][k])/(N-1) -> bf16
// hi/lo planes. 4 rows/block, grid 2048 -> 8 blocks/CU for latency hiding.
__global__ __launch_bounds__(256) void kF(
    const float* __restrict__ s, const float* __restrict__ t,
    const float* __restrict__ b3,
    const int* __restrict__ rank, const int* __restrict__ pos,
    const float* __restrict__ ts, const float* __restrict__ Gs,
    const float* __restrict__ p0, const float* __restrict__ p1,
    short* __restrict__ Mhi, short* __restrict__ Mlo)
{
    int col = threadIdx.x;
    int i0 = blockIdx.x * 4;
    float T0 = p0[(size_t)NCH * FD + col];
    float T1 = p1[(size_t)NCH * FD + col];
    float c = b3[0];
    const float inv = 1.0f / (float)(NR - 1);
    #pragma unroll
    for (int r = 0; r < 4; ++r){
        int i = i0 + r;
        float sic = s[i] + c;
        float diag = leaky_f(sic + t[i]);
        int ps = pos[i];
        int rk = rank[i];
        int ch = ps >> 3;
        float P0 = p0[(size_t)ch * FD + col];
        float P1 = p1[(size_t)ch * FD + col];
        for (int r2 = ch * 8; r2 < ps; ++r2){   // <=7 iters, uniform
            float g2 = Gs[(size_t)r2 * FD + col];
            P0 += g2;
            P1 += ts[r2] * g2;
        }
        float g = Gs[(size_t)rk * FD + col];
        float full = sic * T0 + T1;
        float act  = sic * (T0 - P0) + (T1 - P1);
        float m = (0.1f * full + 0.9f * act - diag * g) * inv;
        unsigned short h = f2bf(m);
        Mhi[(size_t)i * FD + col] = (short)h;
        Mlo[(size_t)i * FD + col] = (short)f2bf(m - bf2f(h));
    }
}

// ---------------------------------------------------------------------------
extern "C" void kernel_launch(void* const* d_in, const int* in_sizes, int n_in,
                              void* d_out, int out_size, void* d_ws, size_t ws_size,
                              hipStream_t stream)
{
    const float* x  = (const float*)d_in[0];
    const float* W3 = (const float*)d_in[1];
    const float* b3 = (const float*)d_in[2];
    const float* W6 = (const float*)d_in[3];
    const float* b6 = (const float*)d_in[4];
    const float* W5 = (const float*)d_in[5];
    const float* b5 = (const float*)d_in[6];
    float* out = (float*)d_out;

    char* ws = (char*)d_ws;
    size_t off = 0;
    auto alloc = [&](size_t bytes) -> void* {
        void* p = ws + off;
        off += (bytes + 255) & ~(size_t)255;
        return p;
    };
    float*  s    = (float*)alloc(NR * 4);
    float*  t    = (float*)alloc(NR * 4);
    float*  ts   = (float*)alloc(NR * 4);
    int*    rank = (int*)  alloc(NR * 4);
    int*    pos  = (int*)  alloc(NR * 4);
    float*  p0   = (float*)alloc((size_t)(NCH + 1) * FD * 4);
    float*  p1   = (float*)alloc((size_t)(NCH + 1) * FD * 4);
    short*  W6hi = (short*)alloc(FD * FD * 2);
    short*  W6lo = (short*)alloc(FD * FD * 2);
    short*  W5hi = (short*)alloc(FD * FD * 2);
    short*  W5lo = (short*)alloc(FD * FD * 2);
    short*  xhi  = (short*)alloc((size_t)NR * FD * 2);
    short*  xlo  = (short*)alloc((size_t)NR * FD * 2);
    short*  Mhi  = (short*)alloc((size_t)NR * FD * 2);
    short*  Mlo  = (short*)alloc((size_t)NR * FD * 2);
    float*  Gs   = (float*)alloc((size_t)NR * FD * 4);
    (void)ws_size; (void)in_sizes; (void)n_in; (void)out_size;

    kA<<<dim3(512 + NR / 4), dim3(256), 0, stream>>>(
        x, W3, W6, W5, s, t, rank, pos, xhi, xlo, W6hi, W6lo, W5hi, W5lo);
    kB<<<dim3(32, 32), dim3(256), 0, stream>>>(t, s, b3, rank, pos);
    kGemm<true, false><<<dim3(1024), dim3(256), 0, stream>>>(
        xhi, xlo, W6hi, W6lo, b6, nullptr, rank, t, ts, Gs);
    kD<<<dim3(NCH), dim3(256), 0, stream>>>(Gs, ts, p0, p1);
    kE<<<dim3(512), dim3(64), 0, stream>>>(p0, p1);
    kF<<<dim3(NR / 4), dim3(256), 0, stream>>>(
        s, t, b3, rank, pos, ts, Gs, p0, p1, Mhi, Mlo);
    kGemm<false, true><<<dim3(1024), dim3(256), 0, stream>>>(
        Mhi, Mlo, W5hi, W5lo, b5, x, nullptr, nullptr, nullptr, out);
}